// Round 8
// baseline (342.769 us; speedup 1.0000x reference)
//
#include <hip/hip_runtime.h>
#include <cstddef>

// Problem constants
constexpr int Bn  = 512;
constexpr int Dd  = 960;
constexpr int RL  = 16;
constexpr int RD  = 32;
constexpr int LPp = 16;
constexpr int LHh = 384;
constexpr int DP  = 358;
constexpr int DH  = 154;

typedef float f32x4 __attribute__((ext_vector_type(4)));

struct EncParams {
    const float* X;     // (B, L, 960)
    const int*   mask;  // (B, L) contiguous prefix
    const float* A;     // (L, 16)
    const float* Bc;    // (960, 32)
    const float* Hc;    // (512, dmod)
    const float* W1; const float* b1; const float* g; const float* beta;
    const float* W2; const float* b2;
    int L, dmod, ooff;
};

// =====================================================================
// K0: zero the work-queue counter (ws is poisoned 0xAA by harness).
// =====================================================================
__global__ void zero_kernel(int* __restrict__ q)
{
    if (threadIdx.x == 0) *q = 0;
}

// =====================================================================
// K1: persistent fused per-batch encoder (round-7 structure) with a
// rebuilt stream phase:
//  - A staged per 64-row chunk into LDS (rows >= len zeroed) -> A reads
//    are ds_read broadcasts on lgkmcnt, DECOUPLED from the X vmcnt queue
//    (round 7 serialized one HBM latency per 2 rows because A-loads
//    forced vmcnt(0) each iteration).
//  - X streamed with an 8-row ping-pong register prefetch: next oct's
//    8 nontemporal f32x4 loads issue before current oct's FMAs ->
//    128 B/lane in flight, FMA body covers HBM latency.
// Tail phases (U, z, MLP1, MLP2) as round 7 but with 2-4 independent
// accumulator chains to cut dependent-FMA latency at 2 waves/SIMD.
// =====================================================================
__global__ __launch_bounds__(256)
void persist_kernel(EncParams H, EncParams P, int* __restrict__ qcnt,
                    float* __restrict__ out)
{
    const int t = threadIdx.x;
    __shared__ float Vs[RL][Dd];     // 61440 B (zs/hs reuse after U phase)
    __shared__ float As[64 * RL];    //  4096 B (A chunk, len-zeroed)
    __shared__ float Ush[RL * RD];   //  2048 B
    __shared__ int   s_item, s_len;

    for (;;) {
        __syncthreads();                 // protect LDS reuse across items
        if (t == 0) { s_item = atomicAdd(qcnt, 1); s_len = 0; }
        __syncthreads();
        const int item = s_item;
        if (item >= 2 * Bn) return;
        const bool isH = (item < Bn);
        const EncParams E = isH ? H : P;
        const int b = isH ? item : item - Bn;
        const int CH = isH ? 64 : 16;    // chunk rows (<= L, mult of 8)

        // ---- len = popcount of contiguous-prefix mask row ----
        int loc = 0;
        for (int i = t; i < E.L; i += 256) loc += E.mask[(size_t)b * E.L + i];
        if (loc) atomicAdd(&s_len, loc);
        __syncthreads();
        const int len = s_len;

        // ---- stream phase: V = A^T Xm ----
        float v[RL][4];
        #pragma unroll
        for (int p = 0; p < RL; ++p)
            #pragma unroll
            for (int q = 0; q < 4; ++q) v[p][q] = 0.f;

        const float* Xb = E.X + (size_t)b * E.L * Dd + 4 * t;

        for (int c0 = 0; c0 < len; c0 += CH) {
            __syncthreads();             // As reuse across chunks
            // stage A chunk: As[i][p], rows >= len zeroed (exact: 0*x = 0)
            if (4 * t < CH * RL) {
                const int row = c0 + (t >> 2);
                f32x4 av = {0.f, 0.f, 0.f, 0.f};
                if (row < len)
                    av = *(const f32x4*)(E.A + (size_t)row * RL + (t & 3) * 4);
                *(f32x4*)&As[4 * t] = av;
            }
            __syncthreads();

            if (t < 240) {               // 240 lanes x 4 d-cols = 960
                auto computeOct = [&](int r0, f32x4* x) {
                    #pragma unroll
                    for (int rr = 0; rr < 8; ++rr) {
                        float a[RL];
                        *(f32x4*)&a[0]  = *(const f32x4*)&As[(r0 + rr) * RL + 0];
                        *(f32x4*)&a[4]  = *(const f32x4*)&As[(r0 + rr) * RL + 4];
                        *(f32x4*)&a[8]  = *(const f32x4*)&As[(r0 + rr) * RL + 8];
                        *(f32x4*)&a[12] = *(const f32x4*)&As[(r0 + rr) * RL + 12];
                        #pragma unroll
                        for (int p = 0; p < RL; ++p) {
                            v[p][0] = fmaf(a[p], x[rr][0], v[p][0]);
                            v[p][1] = fmaf(a[p], x[rr][1], v[p][1]);
                            v[p][2] = fmaf(a[p], x[rr][2], v[p][2]);
                            v[p][3] = fmaf(a[p], x[rr][3], v[p][3]);
                        }
                    }
                };
                const int nocts = CH >> 3;           // 8 (H) or 2 (P), even
                const float* base = Xb + (size_t)c0 * Dd;
                f32x4 xa[8], xb[8];
                #pragma unroll
                for (int rr = 0; rr < 8; ++rr)
                    xa[rr] = __builtin_nontemporal_load(
                        (const f32x4*)(base + (size_t)rr * Dd));
                for (int oc = 0; oc < nocts; oc += 2) {
                    const float* pb = base + (size_t)(oc + 1) * 8 * Dd;
                    #pragma unroll
                    for (int rr = 0; rr < 8; ++rr)
                        xb[rr] = __builtin_nontemporal_load(
                            (const f32x4*)(pb + (size_t)rr * Dd));
                    computeOct(oc * 8, xa);          // hides xb latency
                    if (oc + 2 < nocts) {
                        const float* pa = base + (size_t)(oc + 2) * 8 * Dd;
                        #pragma unroll
                        for (int rr = 0; rr < 8; ++rr)
                            xa[rr] = __builtin_nontemporal_load(
                                (const f32x4*)(pa + (size_t)rr * Dd));
                    }
                    computeOct((oc + 1) * 8, xb);    // hides xa latency
                }
            }
        }
        __syncthreads();
        if (t < 240) {
            #pragma unroll
            for (int p = 0; p < RL; ++p)
                *(f32x4*)&Vs[p][4 * t] = *(f32x4*)&v[p][0];
        }
        __syncthreads();

        // ---- U phase: U = V * Bc (4 independent chains) ----
        {
            const int p = t >> 5, r = t & 31;
            float u00 = 0.f, u01 = 0.f, u10 = 0.f, u11 = 0.f;
            for (int dd = 0; dd < Dd; dd += 8) {
                f32x4 v0a = *(const f32x4*)&Vs[p][dd];
                f32x4 v0b = *(const f32x4*)&Vs[p][dd + 4];
                f32x4 v1a = *(const f32x4*)&Vs[p + 8][dd];
                f32x4 v1b = *(const f32x4*)&Vs[p + 8][dd + 4];
                #pragma unroll
                for (int q = 0; q < 4; ++q) {
                    float bca = E.Bc[(size_t)(dd + q) * RD + r];
                    float bcb = E.Bc[(size_t)(dd + 4 + q) * RD + r];
                    u00 = fmaf(v0a[q], bca, u00);
                    u01 = fmaf(v0b[q], bcb, u01);
                    u10 = fmaf(v1a[q], bca, u10);
                    u11 = fmaf(v1b[q], bcb, u11);
                }
            }
            Ush[p * RD + r]       = u00 + u01;
            Ush[(p + 8) * RD + r] = u10 + u11;
        }
        __syncthreads();

        // ---- z phase: z = vec(U) @ Hc (4 chains; zs/hs reuse Vs) ----
        float* zs = &Vs[0][0];
        float* hs = &Vs[0][0] + 512;
        for (int j = t; j < E.dmod; j += 256) {
            float a0 = 0.f, a1 = 0.f, a2 = 0.f, a3 = 0.f;
            #pragma unroll 4
            for (int i = 0; i < RL * RD; i += 4) {
                a0 = fmaf(Ush[i],     E.Hc[(size_t)i * E.dmod + j],       a0);
                a1 = fmaf(Ush[i + 1], E.Hc[(size_t)(i + 1) * E.dmod + j], a1);
                a2 = fmaf(Ush[i + 2], E.Hc[(size_t)(i + 2) * E.dmod + j], a2);
                a3 = fmaf(Ush[i + 3], E.Hc[(size_t)(i + 3) * E.dmod + j], a3);
            }
            zs[j] = (a0 + a1) + (a2 + a3);
        }
        __syncthreads();

        // ---- MLP layer 1 + BN + ReLU (2 chains) ----
        const float bscale = rsqrtf(1.f + 1e-5f);
        const int K = E.dmod;
        for (int c = t; c < K; c += 256) {
            float a0 = E.b1[c], a1 = 0.f;
            #pragma unroll 4
            for (int k = 0; k < K; k += 2) {   // K even (358/154)
                a0 = fmaf(zs[k],     E.W1[(size_t)k * K + c],       a0);
                a1 = fmaf(zs[k + 1], E.W1[(size_t)(k + 1) * K + c], a1);
            }
            float acc = a0 + a1;
            acc = fmaf(acc, E.g[c] * bscale, E.beta[c]);
            hs[c] = fmaxf(acc, 0.f);
        }
        __syncthreads();

        // ---- MLP layer 2 + concat store (2 chains) ----
        for (int c = t; c < K; c += 256) {
            float a0 = E.b2[c], a1 = 0.f;
            #pragma unroll 4
            for (int k = 0; k < K; k += 2) {
                a0 = fmaf(hs[k],     E.W2[(size_t)k * K + c],       a0);
                a1 = fmaf(hs[k + 1], E.W2[(size_t)(k + 1) * K + c], a1);
            }
            out[(size_t)b * (DP + DH) + E.ooff + c] = a0 + a1;
        }
        // loop: top-of-loop __syncthreads protects Vs/Ush/As reuse
    }
}

// =====================================================================
extern "C" void kernel_launch(void* const* d_in, const int* in_sizes, int n_in,
                              void* d_out, int out_size, void* d_ws, size_t ws_size,
                              hipStream_t stream)
{
    EncParams P, H;
    P.X    = (const float*)d_in[0];
    H.X    = (const float*)d_in[1];
    P.mask = (const int*)  d_in[2];
    H.mask = (const int*)  d_in[3];
    P.Bc   = (const float*)d_in[4];
    P.A    = (const float*)d_in[5];
    P.Hc   = (const float*)d_in[6];
    P.W1   = (const float*)d_in[7];
    P.b1   = (const float*)d_in[8];
    P.g    = (const float*)d_in[9];
    P.beta = (const float*)d_in[10];
    P.W2   = (const float*)d_in[11];
    P.b2   = (const float*)d_in[12];
    H.Bc   = (const float*)d_in[13];
    H.A    = (const float*)d_in[14];
    H.Hc   = (const float*)d_in[15];
    H.W1   = (const float*)d_in[16];
    H.b1   = (const float*)d_in[17];
    H.g    = (const float*)d_in[18];
    H.beta = (const float*)d_in[19];
    H.W2   = (const float*)d_in[20];
    H.b2   = (const float*)d_in[21];
    P.L = LPp;  P.dmod = DP;  P.ooff = 0;
    H.L = LHh;  H.dmod = DH;  H.ooff = DP;

    float* outp = (float*)d_out;
    int*   qcnt = (int*)d_ws;

    zero_kernel<<<dim3(1), dim3(64), 0, stream>>>(qcnt);
    persist_kernel<<<dim3(512), dim3(256), 0, stream>>>(H, P, qcnt, outp);
}

// Round 9
// 215.182 us; speedup vs baseline: 1.5929x; 1.5929x over previous
//
#include <hip/hip_runtime.h>
#include <cstddef>

// Problem constants
constexpr int Bn  = 512;
constexpr int Dd  = 960;
constexpr int RL  = 16;
constexpr int RD  = 32;
constexpr int LPp = 16;
constexpr int LHh = 384;
constexpr int DP  = 358;
constexpr int DH  = 154;
constexpr int CH  = 128;   // A-chunk rows staged in LDS

typedef float f32x4 __attribute__((ext_vector_type(4)));

struct EncParams {
    const float* X;     // (B, L, 960)
    const int*   mask;  // (B, L) contiguous prefix
    const float* A;     // (L, 16)
    const float* Bc;    // (960, 32)
    const float* Hc;    // (512, dmod)
    const float* W1; const float* b1; const float* g; const float* beta;
    const float* W2; const float* b2;
    int L, dmod, ooff;
};

// =====================================================================
// K0: zero the work-queue counter (ws is poisoned 0xAA by harness).
// =====================================================================
__global__ void zero_kernel(int* __restrict__ q)
{
    if (threadIdx.x == 0) *q = 0;
}

// =====================================================================
// K1: persistent fused per-batch encoder, occupancy-first stream.
// 512-thread blocks (8 waves), grid 512 = 2 blocks/CU resident
//   -> 16 waves/CU (VGPR pool 2048 / ~110 regs caps at ~16: max usable).
// Stream: 2 row-groups x 240 lanes x f32x4 (16B) over interleaved rows;
//   ONE-row lookahead only (2 loads in flight/lane = 32 KB/CU in flight
//   > 22 KB needed for this CU's HBM share; r8 showed deep manual
//   pipelines collapse under VGPR pressure - TLP is the robust lever).
// A staged per 128-row chunk in LDS (rows >= len zeroed) -> A reads on
//   lgkmcnt, off the X vmcnt queue (r7's serializer).
// Tail (U, z, MLP1, MLP2, concat store) = r7's proven body at 512 thr;
//   runs under the other resident block's stream (r3's overlap lesson).
// Work queue: H items (heavy) first -> LPT; P items backfill.
// =====================================================================
__global__ __launch_bounds__(512)
void persist_kernel(EncParams H, EncParams P, int* __restrict__ qcnt,
                    float* __restrict__ out)
{
    const int t = threadIdx.x;
    __shared__ float Vs[RL][Dd];     // 61440 B (zs/hs reuse after U)
    __shared__ float As[CH * RL];    //  8192 B
    __shared__ float Ush[RL * RD];   //  2048 B
    __shared__ int   s_item, s_len;

    const int  g   = t >> 8;         // row-group 0..1
    const int  w   = t & 255;        // lane within group
    const bool act = (w < 240);      // 240 lanes x 4 cols = 960
    const int  col = 4 * w;

    for (;;) {
        __syncthreads();             // protect LDS reuse across items
        if (t == 0) { s_item = atomicAdd(qcnt, 1); s_len = 0; }
        __syncthreads();
        const int item = s_item;
        if (item >= 2 * Bn) return;
        const bool isH = (item < Bn);
        const EncParams E = isH ? H : P;
        const int b = isH ? item : item - Bn;

        // ---- len = popcount of contiguous-prefix mask row ----
        int loc = 0;
        for (int i = t; i < E.L; i += 512) loc += E.mask[(size_t)b * E.L + i];
        if (loc) atomicAdd(&s_len, loc);
        __syncthreads();
        const int len = s_len;

        // ---- stream phase: V = A^T Xm, group g owns rows l%2==g ----
        float v[RL][4];
        #pragma unroll
        for (int p = 0; p < RL; ++p)
            { v[p][0] = 0.f; v[p][1] = 0.f; v[p][2] = 0.f; v[p][3] = 0.f; }

        const float* Xb = E.X + (size_t)b * E.L * Dd;

        for (int c0 = 0; c0 < len; c0 += CH) {
            __syncthreads();         // prior chunk's As reads done
            {   // stage A chunk (128 rows x 16), rows >= len zeroed
                const int row = c0 + (t >> 2);
                f32x4 av = {0.f, 0.f, 0.f, 0.f};
                if (row < len)
                    av = *(const f32x4*)(E.A + (size_t)row * RL + (t & 3) * 4);
                *(f32x4*)&As[(t >> 2) * RL + (t & 3) * 4] = av;
            }
            __syncthreads();

            if (act) {
                const int lim = min(len, c0 + CH);
                int l = c0 + g;
                if (l < lim) {
                    const float* rp = Xb + (size_t)l * Dd + col;
                    f32x4 x = __builtin_nontemporal_load((const f32x4*)rp);
                    for (; l < lim; l += 2) {
                        f32x4 xn = x;
                        if (l + 2 < lim) {      // one-row lookahead
                            rp += 2 * (size_t)Dd;
                            xn = __builtin_nontemporal_load((const f32x4*)rp);
                        }
                        float a[RL];
                        const int lr = l - c0;
                        *(f32x4*)&a[0]  = *(const f32x4*)&As[lr * RL + 0];
                        *(f32x4*)&a[4]  = *(const f32x4*)&As[lr * RL + 4];
                        *(f32x4*)&a[8]  = *(const f32x4*)&As[lr * RL + 8];
                        *(f32x4*)&a[12] = *(const f32x4*)&As[lr * RL + 12];
                        #pragma unroll
                        for (int p = 0; p < RL; ++p) {
                            v[p][0] = fmaf(a[p], x[0], v[p][0]);
                            v[p][1] = fmaf(a[p], x[1], v[p][1]);
                            v[p][2] = fmaf(a[p], x[2], v[p][2]);
                            v[p][3] = fmaf(a[p], x[3], v[p][3]);
                        }
                        x = xn;
                    }
                }
            }
        }

        // ---- combine the two row-groups into Vs ----
        __syncthreads();
        if (g == 0 && act) {
            #pragma unroll
            for (int p = 0; p < RL; ++p)
                *(f32x4*)&Vs[p][col] = *(f32x4*)&v[p][0];
        }
        __syncthreads();
        if (g == 1 && act) {
            #pragma unroll
            for (int p = 0; p < RL; ++p) {
                f32x4 cur = *(const f32x4*)&Vs[p][col];
                cur += *(f32x4*)&v[p][0];
                *(f32x4*)&Vs[p][col] = cur;
            }
        }
        __syncthreads();

        // ---- U phase: thread t = (p,r) computes one U entry ----
        {
            const int p = t >> 5, r = t & 31;
            float u0 = 0.f, u1 = 0.f;
            for (int dd = 0; dd < Dd; dd += 8) {
                f32x4 va = *(const f32x4*)&Vs[p][dd];
                f32x4 vb = *(const f32x4*)&Vs[p][dd + 4];
                #pragma unroll
                for (int q = 0; q < 4; ++q) {
                    u0 = fmaf(va[q], E.Bc[(size_t)(dd + q) * RD + r],     u0);
                    u1 = fmaf(vb[q], E.Bc[(size_t)(dd + 4 + q) * RD + r], u1);
                }
            }
            Ush[t] = u0 + u1;        // t == p*32 + r
        }
        __syncthreads();

        // ---- z phase: z = vec(U) @ Hc (zs/hs reuse dead Vs space) ----
        float* zs = &Vs[0][0];
        float* hs = zs + 512;
        for (int j = t; j < E.dmod; j += 512) {
            float a0 = 0.f, a1 = 0.f, a2 = 0.f, a3 = 0.f;
            #pragma unroll 4
            for (int i = 0; i < RL * RD; i += 4) {
                a0 = fmaf(Ush[i],     E.Hc[(size_t)i * E.dmod + j],       a0);
                a1 = fmaf(Ush[i + 1], E.Hc[(size_t)(i + 1) * E.dmod + j], a1);
                a2 = fmaf(Ush[i + 2], E.Hc[(size_t)(i + 2) * E.dmod + j], a2);
                a3 = fmaf(Ush[i + 3], E.Hc[(size_t)(i + 3) * E.dmod + j], a3);
            }
            zs[j] = (a0 + a1) + (a2 + a3);
        }
        __syncthreads();

        // ---- MLP layer 1 + BN + ReLU ----
        const float bscale = rsqrtf(1.f + 1e-5f);
        const int K = E.dmod;
        for (int c = t; c < K; c += 512) {
            float a0 = E.b1[c], a1 = 0.f;
            #pragma unroll 4
            for (int k = 0; k < K; k += 2) {       // K even (358/154)
                a0 = fmaf(zs[k],     E.W1[(size_t)k * K + c],       a0);
                a1 = fmaf(zs[k + 1], E.W1[(size_t)(k + 1) * K + c], a1);
            }
            float acc = a0 + a1;
            acc = fmaf(acc, E.g[c] * bscale, E.beta[c]);
            hs[c] = fmaxf(acc, 0.f);
        }
        __syncthreads();

        // ---- MLP layer 2 + concat store ----
        for (int c = t; c < K; c += 512) {
            float a0 = E.b2[c], a1 = 0.f;
            #pragma unroll 4
            for (int k = 0; k < K; k += 2) {
                a0 = fmaf(hs[k],     E.W2[(size_t)k * K + c],       a0);
                a1 = fmaf(hs[k + 1], E.W2[(size_t)(k + 1) * K + c], a1);
            }
            out[(size_t)b * (DP + DH) + E.ooff + c] = a0 + a1;
        }
        // loop: top-of-loop barrier protects Vs/As/Ush reuse
    }
}

// =====================================================================
extern "C" void kernel_launch(void* const* d_in, const int* in_sizes, int n_in,
                              void* d_out, int out_size, void* d_ws, size_t ws_size,
                              hipStream_t stream)
{
    EncParams P, H;
    P.X    = (const float*)d_in[0];
    H.X    = (const float*)d_in[1];
    P.mask = (const int*)  d_in[2];
    H.mask = (const int*)  d_in[3];
    P.Bc   = (const float*)d_in[4];
    P.A    = (const float*)d_in[5];
    P.Hc   = (const float*)d_in[6];
    P.W1   = (const float*)d_in[7];
    P.b1   = (const float*)d_in[8];
    P.g    = (const float*)d_in[9];
    P.beta = (const float*)d_in[10];
    P.W2   = (const float*)d_in[11];
    P.b2   = (const float*)d_in[12];
    H.Bc   = (const float*)d_in[13];
    H.A    = (const float*)d_in[14];
    H.Hc   = (const float*)d_in[15];
    H.W1   = (const float*)d_in[16];
    H.b1   = (const float*)d_in[17];
    H.g    = (const float*)d_in[18];
    H.beta = (const float*)d_in[19];
    H.W2   = (const float*)d_in[20];
    H.b2   = (const float*)d_in[21];
    P.L = LPp;  P.dmod = DP;  P.ooff = 0;
    H.L = LHh;  H.dmod = DH;  H.ooff = DP;

    float* outp = (float*)d_out;
    int*   qcnt = (int*)d_ws;

    zero_kernel<<<dim3(1), dim3(64), 0, stream>>>(qcnt);
    persist_kernel<<<dim3(512), dim3(512), 0, stream>>>(H, P, qcnt, outp);
}